// Round 1
// baseline (687.595 us; speedup 1.0000x reference)
//
#include <hip/hip_runtime.h>
#include <hip/hip_bf16.h>
#include <cmath>
#include <cstdint>

// SparseMoE: B=2,S=2048 -> 4096 tokens, E=1024, N=8 experts, H=4096, top_k=2.
// R7: 256x256/BK=64 8-wave 4-phase-per-K-tile grouped GEMM (m201-style template):
//   - 128KB LDS, double-buffered, linear gload_lds dest + inverse-swizzled global
//     source + swizzled ds_read_b128 (slot ^= row&7 -> conflict-free reads)
//   - counted s_waitcnt vmcnt(4) once per K-tile (never 0 in main loop)
//   - raw s_barrier (2/phase), s_setprio(1) around each 16-MFMA cluster
//   - XCD-bijective blockIdx swizzle (m204)
//   - layer2 KSPLIT=4 over blockIdx.y, atomicAdd into pre-zeroed fp32 Y
//   - A&S erf-based exact gelu (|eps|<=1.5e-7), cheap vs libm erff

typedef unsigned short u16;
typedef __attribute__((ext_vector_type(8))) short bf16x8;   // MFMA A/B frag (4 VGPR)
typedef __attribute__((ext_vector_type(4))) float f32x4;    // MFMA C/D frag
typedef __attribute__((ext_vector_type(8))) unsigned short us8;
typedef __attribute__((ext_vector_type(4))) unsigned short us4;

#define TOKENS  4096
#define EDIM    1024
#define NEXP    8
#define HDIM    4096
#define MAXROWS 8192      // top_k(=2) * TOKENS
#define ROWPAD  384       // 256-row tile tail staging may read past cnt
#define MAXTILES 40       // sum ceil(cnt_e/256) <= 32 + 7
#define RBLK    1024      // router blocks (4 tokens each)

#define MFMA16(va, vb, vc) __builtin_amdgcn_mfma_f32_16x16x32_bf16(va, vb, vc, 0, 0, 0)

__device__ __forceinline__ u16 f2bf(float f) {
  __hip_bfloat16 h = __float2bfloat16(f);   // RNE
  return *reinterpret_cast<u16*>(&h);
}
__device__ __forceinline__ int clampk(int k) {
  return k < 1 ? 1 : (k > 8 ? 8 : k);
}
// async global->LDS, 16B/lane; LDS dest = wave-uniform base + lane*16 (HW rule)
__device__ __forceinline__ void async16(void* lds, const void* g) {
  __builtin_amdgcn_global_load_lds((const __attribute__((address_space(1))) void*)g,
                                   (__attribute__((address_space(3))) void*)lds,
                                   16, 0, 0);
}
// exact gelu via A&S 7.1.26 erf (|eps|<=1.5e-7), ~12 VALU ops
__device__ __forceinline__ float gelu_f(float v) {
  const float z = fabsf(v) * 0.70710678118654752f;
  const float t = __builtin_amdgcn_rcpf(fmaf(0.3275911f, z, 1.0f));
  const float p = t * fmaf(t, fmaf(t, fmaf(t, fmaf(t, 1.061405429f, -1.453152027f),
                                           1.421413741f), -0.284496736f), 0.254829592f);
  float er = 1.0f - p * __expf(-z * z);
  er = copysignf(er, v);
  return 0.5f * v * (1.0f + er);
}
// m204 bijective XCD swizzle (8 XCDs)
__device__ __forceinline__ int xcd_swz(int orig, int nwg) {
  const int q = nwg >> 3, r = nwg & 7;
  const int x = orig & 7, l = orig >> 3;
  return (x < r ? x * (q + 1) : r * (q + 1) + (x - r) * q) + l;
}

// ---------- router: logits + top-k + softmax + block-local hist (no atomics) ----------
__global__ void router_k(const float* __restrict__ x, const float* __restrict__ Wr,
                         const float* __restrict__ br, const int* __restrict__ topk_p,
                         int* __restrict__ sel_e, float* __restrict__ sel_w,
                         int* __restrict__ sel_lpos, int* __restrict__ hist_blk) {
  __shared__ int wsel[4][8];
  const int blk = blockIdx.x;
  const int tid = threadIdx.x;
  const int wv = tid >> 6, ln = tid & 63;
  const int t = blk * 4 + wv;
  const int k = clampk(topk_p[0]);
  float acc[NEXP];
#pragma unroll
  for (int n = 0; n < NEXP; ++n) acc[n] = 0.f;
  const float* xr = x + (size_t)t * EDIM;
  for (int ei = ln; ei < EDIM; ei += 64) {
    float xv = xr[ei];
    float4 w0 = *(const float4*)(Wr + ei * NEXP);
    float4 w1 = *(const float4*)(Wr + ei * NEXP + 4);
    acc[0] += xv * w0.x; acc[1] += xv * w0.y; acc[2] += xv * w0.z; acc[3] += xv * w0.w;
    acc[4] += xv * w1.x; acc[5] += xv * w1.y; acc[6] += xv * w1.z; acc[7] += xv * w1.w;
  }
#pragma unroll
  for (int s = 32; s > 0; s >>= 1) {
#pragma unroll
    for (int n = 0; n < NEXP; ++n) acc[n] += __shfl_down(acc[n], s);
  }
  if (ln == 0) {
    float logit[NEXP];
#pragma unroll
    for (int n = 0; n < NEXP; ++n) logit[n] = acc[n] + br[n];
    bool used[NEXP];
#pragma unroll
    for (int n = 0; n < NEXP; ++n) used[n] = false;
    int se[NEXP]; float sw[NEXP];
    for (int j = 0; j < k; ++j) {           // strict > : lowest index wins ties (lax.top_k)
      int bi = 0; float bv = -INFINITY;
      for (int n = 0; n < NEXP; ++n)
        if (!used[n] && logit[n] > bv) { bv = logit[n]; bi = n; }
      used[bi] = true; se[j] = bi; sw[j] = bv;
    }
    float mx = sw[0], sum = 0.f;
    for (int j = 0; j < k; ++j) { sw[j] = expf(sw[j] - mx); sum += sw[j]; }
    float inv = 1.f / sum;
    for (int j = 0; j < k; ++j) {
      sel_e[t * 8 + j] = se[j];
      sel_w[t * 8 + j] = sw[j] * inv;
      wsel[wv][j] = se[j];
    }
  }
  __syncthreads();
  if (tid == 0) {
    int h[NEXP];
#pragma unroll
    for (int e = 0; e < NEXP; ++e) h[e] = 0;
    for (int w = 0; w < 4; ++w)
      for (int j = 0; j < k; ++j) {
        int e = wsel[w][j];
        sel_lpos[(blk * 4 + w) * 8 + j] = h[e]++;
      }
#pragma unroll
    for (int e = 0; e < NEXP; ++e) hist_blk[blk * NEXP + e] = h[e];
  }
}

// ---------- scan: per-expert exclusive scan over 1024 block hists ----------
__global__ void scan_k(const int* __restrict__ hist_blk, int* __restrict__ counts,
                       int* __restrict__ offsets, int* __restrict__ blk_base,
                       int* __restrict__ tmap) {
  __shared__ int sc[NEXP][257];
  __shared__ int offs[NEXP];
  const int tid = threadIdx.x;              // 256 threads, 4 hist rows each
  int h[4][NEXP], part[NEXP];
#pragma unroll
  for (int e = 0; e < NEXP; ++e) part[e] = 0;
#pragma unroll
  for (int r = 0; r < 4; ++r) {
    const int row = tid * 4 + r;
#pragma unroll
    for (int e = 0; e < NEXP; ++e) { h[r][e] = hist_blk[row * NEXP + e]; part[e] += h[r][e]; }
  }
#pragma unroll
  for (int e = 0; e < NEXP; ++e) sc[e][tid] = part[e];
  __syncthreads();
  for (int d = 1; d < 256; d <<= 1) {       // Hillis-Steele inclusive scan x8
    int v[NEXP];
#pragma unroll
    for (int e = 0; e < NEXP; ++e) v[e] = (tid >= d) ? sc[e][tid - d] : 0;
    __syncthreads();
#pragma unroll
    for (int e = 0; e < NEXP; ++e) sc[e][tid] += v[e];
    __syncthreads();
  }
  if (tid == 0) {
    int s = 0;
    for (int e = 0; e < NEXP; ++e) {
      int tot = sc[e][255];
      offsets[e] = s; offs[e] = s; counts[e] = tot; s += tot;
    }
    int nt = 0;
    for (int e = 0; e < NEXP; ++e) {
      int nb = (counts[e] + 255) >> 8;      // 256-row tiles
      for (int b = 0; b < nb && nt < MAXTILES; ++b) tmap[nt++] = (e << 16) | b;
    }
    for (; nt < MAXTILES; ++nt) tmap[nt] = -1;
  }
  __syncthreads();
#pragma unroll
  for (int e = 0; e < NEXP; ++e) {
    int run = offs[e] + sc[e][tid] - part[e];   // absolute exclusive base
#pragma unroll
    for (int r = 0; r < 4; ++r) {
      blk_base[(tid * 4 + r) * NEXP + e] = run;
      run += h[r][e];
    }
  }
}

// ---------- finalize: absolute positions + row->token scatter ----------
__global__ void finalize_k(const int* __restrict__ sel_e, const int* __restrict__ sel_lpos,
                           const int* __restrict__ blk_base, const int* __restrict__ topk_p,
                           int* __restrict__ sel_pos, int* __restrict__ row_token) {
  const int k = clampk(topk_p[0]);
  const int i = blockIdx.x * 256 + threadIdx.x;
  if (i >= TOKENS * k) return;
  const int t = i / k, j = i - t * k;
  const int e = sel_e[t * 8 + j];
  const int pos = blk_base[(t >> 2) * NEXP + e] + sel_lpos[t * 8 + j];
  sel_pos[t * 8 + j] = pos;                 // absolute compact-row index
  row_token[pos] = t;
}

// ---------------- gather+cast: xg[row] = bf16(x[row_token[row]]); zero pad rows ----------------
__global__ void gather_cast_k(const float* __restrict__ x, const int* __restrict__ row_token,
                              const int* __restrict__ counts, u16* __restrict__ xg) {
  __shared__ int tot_s;
  if (threadIdx.x == 0) {
    int t = 0;
#pragma unroll
    for (int e = 0; e < NEXP; ++e) t += counts[e];
    tot_s = t;
  }
  __syncthreads();
  const int row = blockIdx.x;
  u16* dst = xg + (size_t)row * EDIM;
  const int i = threadIdx.x;                // 256 thr x 4 u16
  if (row >= tot_s) {                       // keep pads finite (tail tiles stage them)
    us4 z = {0, 0, 0, 0};
    *(us4*)(dst + i * 4) = z;
    return;
  }
  const float* src = x + (size_t)row_token[row] * EDIM;
  float4 v = *(const float4*)(src + i * 4);
  us4 o; o[0] = f2bf(v.x); o[1] = f2bf(v.y); o[2] = f2bf(v.z); o[3] = f2bf(v.w);
  *(us4*)(dst + i * 4) = o;
}

// ---------------- zero fp32 buffer (Y accumulator) ----------------
__global__ void zero_f32_k(float* __restrict__ p) {
  const size_t i = ((size_t)blockIdx.x * 256 + threadIdx.x) * 4;
  float4 z = {0.f, 0.f, 0.f, 0.f};
  *(float4*)(p + i) = z;
}

// ------ transpose+downcast 1024-wide H-chunks of W1 and W2 ------
__global__ void transpose_k(const float* __restrict__ W1, const float* __restrict__ W2,
                            u16* __restrict__ W1t, u16* __restrict__ W2t,
                            int full, int h0c) {
  __shared__ __align__(16) u16 T[64][68];   // +4 pad
  const int z = blockIdx.z;
  int mat, e, h0;
  if (full) { mat = z < 32 ? 0 : 1; int zz = mat ? z - 32 : z; e = zz >> 2; h0 = (zz & 3) * 1024; }
  else      { mat = z < 8 ? 0 : 1;  e = mat ? z - 8 : z;      h0 = h0c; }
  const size_t oes = full ? (size_t)HDIM * EDIM : (size_t)1024 * 1024;
  const float* in; size_t istride;
  if (mat == 0) { in = W1 + (size_t)e * EDIM * HDIM + h0;            istride = HDIM; }
  else          { in = W2 + (size_t)e * HDIM * EDIM + (size_t)h0 * EDIM; istride = EDIM; }
  const int r0 = blockIdx.y * 64, c0 = blockIdx.x * 64;
  const int tid = threadIdx.x;
#pragma unroll
  for (int it = 0; it < 4; ++it) {
    int cell = it * 256 + tid;              // 1024 cells: rl(64) x c4(16)
    int rl = cell >> 4, c4 = (cell & 15) * 4;
    float4 v = *(const float4*)(in + (size_t)(r0 + rl) * istride + c0 + c4);
    us4 o; o[0] = f2bf(v.x); o[1] = f2bf(v.y); o[2] = f2bf(v.z); o[3] = f2bf(v.w);
    *(us4*)&T[rl][c4] = o;
  }
  __syncthreads();
#pragma unroll
  for (int it = 0; it < 2; ++it) {
    int cell = it * 256 + tid;              // 512 cells: cl(64) x r8(8)
    int cl = cell >> 3, r8 = (cell & 7) * 8;
    us8 o;
#pragma unroll
    for (int j = 0; j < 8; ++j) o[j] = T[r8 + j][cl];
    u16* out;
    if (mat == 0) {  // W1t[e][h][ei]
      int orow = (full ? h0 : 0) + c0 + cl;
      out = W1t + (size_t)e * oes + (size_t)orow * 1024 + r0 + r8;
    } else {         // W2t[e][ep][h]
      int ost = full ? HDIM : 1024;
      out = W2t + (size_t)e * oes + (size_t)(c0 + cl) * ost + (full ? h0 : 0) + r0 + r8;
    }
    *(us8*)out = o;
  }
}

// -------- grouped 256x256 bf16 MFMA GEMM, BK=64, 8-phase (4 phases / K-tile) --------
// LDS 128KB: A[2 buf][256 rows][64 k] @0, B same @64KB. Swizzle: 16B-slot ^= (row&7)
// applied on the GLOBAL source of global_load_lds (LDS dest linear) and on ds_read.
// Per K-tile t (buf = t&1): P1 reads A[mi0-3]+B[ni0-1] (12xb128), stages A.h0(t+1);
// P2 reads B[ni2-3], stages A.h1(t+1); P3 reads A[mi4-7], stages B.h0(t+2);
// P4 stages B.h1(t+2) + vmcnt(4). Each phase: barrier / lgkmcnt(0) / setprio(1) /
// 16 MFMA / setprio(0) / barrier. Stage-vs-read ledger hand-verified (see session notes).
template <int MODE>
__global__ __launch_bounds__(512, 2) void gemm256_k(
    const u16* __restrict__ A, int astride, int kblocks,
    const u16* __restrict__ Bt, size_t b_estride, int bstride,
    const float* __restrict__ bias, int bias_dim, int bias_col0, int bias_on,
    const int* __restrict__ counts, const int* __restrict__ offsets,
    const int* __restrict__ tmap, int NB,
    u16* __restrict__ hid, int hid_stride, float* __restrict__ Y) {
  __shared__ __align__(16) char lds_s[131072];
  const int bid = xcd_swz(blockIdx.x, gridDim.x);
  const int by  = blockIdx.y;               // K-split index (layer2 full path)
  const int tile = bid / NB;
  const int tv = tmap[tile];
  if (tv < 0) return;
  const int n0 = (bid - tile * NB) << 8;
  const int e = tv >> 16;
  const int m0 = (tv & 0xffff) << 8;
  const int cnt = counts[e], off_e = offsets[e];

  const int tid = threadIdx.x;
  const int wv = tid >> 6, ln = tid & 63;
  const int wm = wv >> 2, wn = wv & 3;      // 2M x 4N wave grid; wave owns 128x64

  // ---- staging addressing: linear LDS dest, inverse-swizzled global source ----
  const int trow = tid >> 3;                // 0..63 rows per 8KB chunk
  const int swz  = (tid & 7) ^ (trow & 7);  // 16B slot permutation (involution)
  const size_t koff = (size_t)by * kblocks * 64;
  const u16* gA = A + (size_t)(off_e + m0 + trow) * astride + koff + swz * 8;
  const u16* gB = Bt + (size_t)e * b_estride + (size_t)(n0 + trow) * bstride + koff + swz * 8;
  const size_t a64 = (size_t)astride * 64;
  const size_t b64 = (size_t)bstride * 64;
  char* const lA = lds_s + wv * 1024;
  char* const lB = lds_s + 65536 + wv * 1024;

  auto stA = [&](int buf, int h, int kt) {  // stage A half-tile (128 rows x 64 k)
    const u16* g = gA + (size_t)(2 * h) * a64 + (size_t)kt * 64;
    char* l = lA + (buf << 15) + (h << 14);
    async16(l, g);
    async16(l + 8192, g + a64);
  };
  auto stB = [&](int buf, int h, int kt) {
    const u16* g = gB + (size_t)(2 * h) * b64 + (size_t)kt * 64;
    char* l = lB + (buf << 15) + (h << 14);
    async16(l, g);
    async16(l + 8192, g + b64);
  };

  // ---- swizzled fragment read offsets (bytes) ----
  const int r15 = ln & 15, quad = ln >> 4, rs = r15 & 7;
  const int a_k0 = (wm * 128 + r15) * 128 + (((quad    ) ^ rs) << 4);
  const int a_k1 = (wm * 128 + r15) * 128 + (((quad + 4) ^ rs) << 4);
  const int b_k0 = (wn *  64 + r15) * 128 + (((quad    ) ^ rs) << 4);
  const int b_k1 = (wn *  64 + r15) * 128 + (((quad + 4) ^ rs) << 4);

  f32x4 acc[8][4];
#pragma unroll
  for (int i = 0; i < 8; ++i)
#pragma unroll
    for (int j = 0; j < 4; ++j) acc[i][j] = (f32x4){0.f, 0.f, 0.f, 0.f};

  bf16x8 a0[4], a1[4], b0[4], b1[4];

  // ---- prologue: tile0 B+A, tile1 B; wait tile0 complete (allow tile1 B in flight) ----
  stB(0, 0, 0); stB(0, 1, 0);
  stA(0, 0, 0); stA(0, 1, 0);
  if (kblocks > 1) {
    stB(1, 0, 1); stB(1, 1, 1);
    asm volatile("s_waitcnt vmcnt(4)" ::: "memory");
  } else {
    asm volatile("s_waitcnt vmcnt(0)" ::: "memory");
  }
  __builtin_amdgcn_s_barrier();

  for (int t = 0; t < kblocks; ++t) {
    const int cb = (t & 1) << 15;
    const int nx = (t & 1) ^ 1;
    const char* cA = lds_s + cb;
    const char* cB = lds_s + 65536 + cb;

    // ---------- phase 1 : Q00 (mi0-3 x ni0-1) ----------
#pragma unroll
    for (int mi = 0; mi < 4; ++mi) {
      a0[mi] = *(const bf16x8*)(cA + a_k0 + mi * 2048);
      a1[mi] = *(const bf16x8*)(cA + a_k1 + mi * 2048);
    }
#pragma unroll
    for (int ni = 0; ni < 2; ++ni) {
      b0[ni] = *(const bf16x8*)(cB + b_k0 + ni * 2048);
      b1[ni] = *(const bf16x8*)(cB + b_k1 + ni * 2048);
    }
    if (t + 1 < kblocks) stA(nx, 0, t + 1);
    asm volatile("s_waitcnt lgkmcnt(8)" ::: "memory");
    __builtin_amdgcn_s_barrier();
    asm volatile("s_waitcnt lgkmcnt(0)" ::: "memory");
    __builtin_amdgcn_s_setprio(1);
#pragma unroll
    for (int mi = 0; mi < 4; ++mi)
#pragma unroll
      for (int ni = 0; ni < 2; ++ni) {
        acc[mi][ni] = MFMA16(a0[mi], b0[ni], acc[mi][ni]);
        acc[mi][ni] = MFMA16(a1[mi], b1[ni], acc[mi][ni]);
      }
    __builtin_amdgcn_s_setprio(0);
    __builtin_amdgcn_s_barrier();

    // ---------- phase 2 : Q01 (mi0-3 x ni2-3) ----------
#pragma unroll
    for (int ni = 2; ni < 4; ++ni) {
      b0[ni] = *(const bf16x8*)(cB + b_k0 + ni * 2048);
      b1[ni] = *(const bf16x8*)(cB + b_k1 + ni * 2048);
    }
    if (t + 1 < kblocks) stA(nx, 1, t + 1);
    __builtin_amdgcn_s_barrier();
    asm volatile("s_waitcnt lgkmcnt(0)" ::: "memory");
    __builtin_amdgcn_s_setprio(1);
#pragma unroll
    for (int mi = 0; mi < 4; ++mi)
#pragma unroll
      for (int ni = 2; ni < 4; ++ni) {
        acc[mi][ni] = MFMA16(a0[mi], b0[ni], acc[mi][ni]);
        acc[mi][ni] = MFMA16(a1[mi], b1[ni], acc[mi][ni]);
      }
    __builtin_amdgcn_s_setprio(0);
    __builtin_amdgcn_s_barrier();

    // ---------- phase 3 : Q10 (mi4-7 x ni0-1) ----------
#pragma unroll
    for (int mi = 0; mi < 4; ++mi) {
      a0[mi] = *(const bf16x8*)(cA + a_k0 + (mi + 4) * 2048);
      a1[mi] = *(const bf16x8*)(cA + a_k1 + (mi + 4) * 2048);
    }
    if (t + 2 < kblocks) stB(t & 1, 0, t + 2);   // cur-buf B last read in P2
    __builtin_amdgcn_s_barrier();
    asm volatile("s_waitcnt lgkmcnt(0)" ::: "memory");
    __builtin_amdgcn_s_setprio(1);
#pragma unroll
    for (int mi = 0; mi < 4; ++mi)
#pragma unroll
      for (int ni = 0; ni < 2; ++ni) {
        acc[mi + 4][ni] = MFMA16(a0[mi], b0[ni], acc[mi + 4][ni]);
        acc[mi + 4][ni] = MFMA16(a1[mi], b1[ni], acc[mi + 4][ni]);
      }
    __builtin_amdgcn_s_setprio(0);
    __builtin_amdgcn_s_barrier();

    // ---------- phase 4 : Q11 (mi4-7 x ni2-3), counted vmcnt ----------
    if (t + 2 < kblocks) {
      stB(t & 1, 1, t + 2);
      asm volatile("s_waitcnt vmcnt(4)" ::: "memory");  // allow B(t+2) in flight
    } else {
      asm volatile("s_waitcnt vmcnt(0)" ::: "memory");
    }
    __builtin_amdgcn_s_barrier();
    __builtin_amdgcn_s_setprio(1);
#pragma unroll
    for (int mi = 0; mi < 4; ++mi)
#pragma unroll
      for (int ni = 2; ni < 4; ++ni) {
        acc[mi + 4][ni] = MFMA16(a0[mi], b0[ni], acc[mi + 4][ni]);
        acc[mi + 4][ni] = MFMA16(a1[mi], b1[ni], acc[mi + 4][ni]);
      }
    __builtin_amdgcn_s_setprio(0);
    __builtin_amdgcn_s_barrier();
  }

  // ---- epilogue: D row = quad*4+r, col = r15 (m89/m91-verified layout) ----
  const int col0 = n0 + wn * 64 + r15;
  float bv[4];
#pragma unroll
  for (int ni = 0; ni < 4; ++ni) {
    const float b = bias[(size_t)e * bias_dim + bias_col0 + col0 + ni * 16];
    bv[ni] = (MODE == 0) ? b : ((bias_on && by == 0) ? b : 0.f);
  }
#pragma unroll
  for (int mi = 0; mi < 8; ++mi) {
    const int mb = m0 + wm * 128 + mi * 16 + quad * 4;
#pragma unroll
    for (int ni = 0; ni < 4; ++ni) {
      const int nc = col0 + ni * 16;
#pragma unroll
      for (int r = 0; r < 4; ++r) {
        const int m = mb + r;
        if (m < cnt) {
          const float v = acc[mi][ni][r] + bv[ni];
          if (MODE == 0) {
            hid[(size_t)(off_e + m) * hid_stride + nc] = f2bf(gelu_f(v));
          } else {
            atomicAdd(&Y[(size_t)(off_e + m) * EDIM + nc], v);
          }
        }
      }
    }
  }
}

// ---------------- weighted combine over top-k rows (absolute sel_pos) ----------------
__global__ void combine_k(const float* __restrict__ Y, const int* __restrict__ sel_pos,
                          const float* __restrict__ sel_w, const int* __restrict__ topk_p,
                          float* __restrict__ out) {
  const int t = blockIdx.x;
  const int tid = threadIdx.x;              // 256 thr x 4 floats
  const int k = clampk(topk_p[0]);
  float a0 = 0.f, a1 = 0.f, a2 = 0.f, a3 = 0.f;
  for (int j = 0; j < k; ++j) {
    const float w = sel_w[t * 8 + j];
    const size_t row = (size_t)sel_pos[t * 8 + j];
    const float4 v = *(const float4*)(Y + row * EDIM + tid * 4);
    a0 += w * v.x; a1 += w * v.y; a2 += w * v.z; a3 += w * v.w;
  }
  float4 o; o.x = a0; o.y = a1; o.z = a2; o.w = a3;
  *(float4*)(out + (size_t)t * EDIM + tid * 4) = o;
}

extern "C" void kernel_launch(void* const* d_in, const int* in_sizes, int n_in,
                              void* d_out, int out_size, void* d_ws, size_t ws_size,
                              hipStream_t stream) {
  const float* x   = (const float*)d_in[0];
  const float* Wr  = (const float*)d_in[1];
  const float* br  = (const float*)d_in[2];
  const float* W1  = (const float*)d_in[3];
  const float* b1  = (const float*)d_in[4];
  const float* W2  = (const float*)d_in[5];
  const float* b2  = (const float*)d_in[6];
  const int* topk  = (const int*)d_in[7];
  float* out = (float*)d_out;

  char* ws = (char*)d_ws;
  size_t o = 0;
  auto alloc = [&](size_t bytes) -> char* {
    char* p = ws + o; o += (bytes + 255) & ~(size_t)255; return p;
  };
  int*   counts    = (int*)alloc(NEXP * 4);
  int*   offsets   = (int*)alloc(NEXP * 4);
  int*   tmap      = (int*)alloc(MAXTILES * 4);
  int*   sel_e     = (int*)alloc((size_t)TOKENS * 8 * 4);
  int*   sel_pos   = (int*)alloc((size_t)TOKENS * 8 * 4);
  int*   sel_lpos  = (int*)alloc((size_t)TOKENS * 8 * 4);
  float* sel_w     = (float*)alloc((size_t)TOKENS * 8 * 4);
  int*   row_token = (int*)alloc((size_t)TOKENS * 8 * 4);
  int*   hist_blk  = (int*)alloc((size_t)RBLK * NEXP * 4);
  int*   blk_base  = (int*)alloc((size_t)RBLK * NEXP * 4);
  u16*   xg        = (u16*)alloc((size_t)(MAXROWS + ROWPAD) * EDIM * 2);  // 17.6 MB
  float* Y         = (float*)alloc((size_t)MAXROWS * EDIM * 4);           // 33.6 MB

  // decide path from remaining ws
  const size_t full_need  = ((size_t)NEXP * HDIM * EDIM * 2) * 2            // W1t+W2t 134.2 MB
                          + (size_t)(MAXROWS + ROWPAD) * HDIM * 2 + 4096;   // hid 70.3 MB
  const bool full = (ws_size - o) >= full_need;
  u16 *W1t, *W2t, *hid;
  if (full) {
    W1t = (u16*)alloc((size_t)NEXP * HDIM * EDIM * 2);
    W2t = (u16*)alloc((size_t)NEXP * HDIM * EDIM * 2);
    hid = (u16*)alloc((size_t)(MAXROWS + ROWPAD) * HDIM * 2);
  } else {
    W1t = (u16*)alloc((size_t)NEXP * 1024 * 1024 * 2);
    W2t = (u16*)alloc((size_t)NEXP * 1024 * 1024 * 2);
    hid = (u16*)alloc((size_t)(MAXROWS + ROWPAD) * 1024 * 2);
  }

  zero_f32_k<<<dim3((MAXROWS * EDIM) / 1024), dim3(256), 0, stream>>>(Y);
  router_k<<<dim3(RBLK), dim3(256), 0, stream>>>(x, Wr, br, topk,
                                                 sel_e, sel_w, sel_lpos, hist_blk);
  scan_k<<<dim3(1), dim3(256), 0, stream>>>(hist_blk, counts, offsets, blk_base, tmap);
  finalize_k<<<dim3(TOKENS * 8 / 256), dim3(256), 0, stream>>>(sel_e, sel_lpos, blk_base,
                                                               topk, sel_pos, row_token);
  gather_cast_k<<<dim3(MAXROWS + ROWPAD), dim3(256), 0, stream>>>(x, row_token, counts, xg);

  if (full) {
    transpose_k<<<dim3(16, 16, 64), dim3(256), 0, stream>>>(W1, W2, W1t, W2t, 1, 0);
    // layer 1: N=4096 merged, K=1024 (16 K-tiles)
    gemm256_k<0><<<dim3(MAXTILES * 16, 1), dim3(512), 0, stream>>>(
        xg, EDIM, 16, W1t, (size_t)HDIM * EDIM, EDIM,
        b1, HDIM, 0, 1, counts, offsets, tmap, 16, hid, HDIM, nullptr);
    // layer 2: K=4096 split 4 ways over blockIdx.y (16 K-tiles each), atomicAdd into Y
    gemm256_k<1><<<dim3(MAXTILES * 4, 4), dim3(512), 0, stream>>>(
        hid, HDIM, 16, W2t, (size_t)HDIM * EDIM, HDIM,
        b2, EDIM, 0, 1, counts, offsets, tmap, 4, nullptr, 0, Y);
  } else {
    for (int c = 0; c < 4; ++c) {
      const int h0 = c * 1024;
      transpose_k<<<dim3(16, 16, 16), dim3(256), 0, stream>>>(W1, W2, W1t, W2t, 0, h0);
      gemm256_k<0><<<dim3(MAXTILES * 4, 1), dim3(512), 0, stream>>>(
          xg, EDIM, 16, W1t, (size_t)1024 * 1024, 1024,
          b1, HDIM, h0, 1, counts, offsets, tmap, 4, hid, 1024, nullptr);
      gemm256_k<1><<<dim3(MAXTILES * 4, 1), dim3(512), 0, stream>>>(
          hid, 1024, 16, W2t, (size_t)1024 * 1024, 1024,
          b2, EDIM, 0, (c == 0) ? 1 : 0, counts, offsets, tmap, 4, nullptr, 0, Y);
    }
  }
  combine_k<<<dim3(TOKENS), dim3(256), 0, stream>>>(Y, sel_pos, sel_w, topk, out);
}

// Round 2
// 661.533 us; speedup vs baseline: 1.0394x; 1.0394x over previous
//
#include <hip/hip_runtime.h>
#include <hip/hip_bf16.h>
#include <cmath>
#include <cstdint>

// SparseMoE: B=2,S=2048 -> 4096 tokens, E=1024, N=8 experts, H=4096, top_k=2.
// R8: 256x256/BK=64 8-wave 2-phase double-buffered grouped GEMM (m230/m248-proven
// structure, 655-682 TF same-shape evidence):
//   - 128KB LDS, double-buffered; linear gload_lds dest + inverse-swizzled global
//     source + swizzled ds_read_b128 (16B-slot ^= row&7 -> 0 bank conflicts, R7-verified)
//   - per K-tile: reads(A0+B) -> stage(t+1 -> buf^1) -> 32 MFMA -> reads(A1)
//     -> 32 MFMA -> __syncthreads()   [no inline asm; syncthreads' vmcnt(0) drain
//     sits ~2.8K cyc after stage-issue -> HBM latency covered]
//   - NO xcd swizzle (R7 post-mortem: it concentrated all tmap<0 dead blocks on
//     XCD7 -> 12.5% of chip idle); HW round-robin spreads dead blocks evenly
//   - layer2 KSPLIT=4 over blockIdx.y, atomicAdd into pre-zeroed fp32 Y
//     (zeroing fused into gather_cast_k)
//   - A&S erf-based exact gelu

typedef unsigned short u16;
typedef __attribute__((ext_vector_type(8))) short bf16x8;   // MFMA A/B frag (4 VGPR)
typedef __attribute__((ext_vector_type(4))) float f32x4;    // MFMA C/D frag
typedef __attribute__((ext_vector_type(8))) unsigned short us8;
typedef __attribute__((ext_vector_type(4))) unsigned short us4;

#define TOKENS  4096
#define EDIM    1024
#define NEXP    8
#define HDIM    4096
#define MAXROWS 8192      // top_k(=2) * TOKENS
#define ROWPAD  384       // 256-row tile tail staging may read past cnt
#define MAXTILES 40       // sum ceil(cnt_e/256) <= 32 + 7
#define RBLK    1024      // router blocks (4 tokens each)

#define MFMA16(va, vb, vc) __builtin_amdgcn_mfma_f32_16x16x32_bf16(va, vb, vc, 0, 0, 0)

__device__ __forceinline__ u16 f2bf(float f) {
  __hip_bfloat16 h = __float2bfloat16(f);   // RNE
  return *reinterpret_cast<u16*>(&h);
}
__device__ __forceinline__ int clampk(int k) {
  return k < 1 ? 1 : (k > 8 ? 8 : k);
}
// async global->LDS, 16B/lane; LDS dest = wave-uniform base + lane*16 (HW rule)
__device__ __forceinline__ void async16(void* lds, const void* g) {
  __builtin_amdgcn_global_load_lds((const __attribute__((address_space(1))) void*)g,
                                   (__attribute__((address_space(3))) void*)lds,
                                   16, 0, 0);
}
// exact gelu via A&S 7.1.26 erf (|eps|<=1.5e-7), ~12 VALU ops
__device__ __forceinline__ float gelu_f(float v) {
  const float z = fabsf(v) * 0.70710678118654752f;
  const float t = __builtin_amdgcn_rcpf(fmaf(0.3275911f, z, 1.0f));
  const float p = t * fmaf(t, fmaf(t, fmaf(t, fmaf(t, 1.061405429f, -1.453152027f),
                                           1.421413741f), -0.284496736f), 0.254829592f);
  float er = 1.0f - p * __expf(-z * z);
  er = copysignf(er, v);
  return 0.5f * v * (1.0f + er);
}

// ---------- router: logits + top-k + softmax + block-local hist (no atomics) ----------
__global__ void router_k(const float* __restrict__ x, const float* __restrict__ Wr,
                         const float* __restrict__ br, const int* __restrict__ topk_p,
                         int* __restrict__ sel_e, float* __restrict__ sel_w,
                         int* __restrict__ sel_lpos, int* __restrict__ hist_blk) {
  __shared__ int wsel[4][8];
  const int blk = blockIdx.x;
  const int tid = threadIdx.x;
  const int wv = tid >> 6, ln = tid & 63;
  const int t = blk * 4 + wv;
  const int k = clampk(topk_p[0]);
  float acc[NEXP];
#pragma unroll
  for (int n = 0; n < NEXP; ++n) acc[n] = 0.f;
  const float* xr = x + (size_t)t * EDIM;
  for (int ei = ln; ei < EDIM; ei += 64) {
    float xv = xr[ei];
    float4 w0 = *(const float4*)(Wr + ei * NEXP);
    float4 w1 = *(const float4*)(Wr + ei * NEXP + 4);
    acc[0] += xv * w0.x; acc[1] += xv * w0.y; acc[2] += xv * w0.z; acc[3] += xv * w0.w;
    acc[4] += xv * w1.x; acc[5] += xv * w1.y; acc[6] += xv * w1.z; acc[7] += xv * w1.w;
  }
#pragma unroll
  for (int s = 32; s > 0; s >>= 1) {
#pragma unroll
    for (int n = 0; n < NEXP; ++n) acc[n] += __shfl_down(acc[n], s);
  }
  if (ln == 0) {
    float logit[NEXP];
#pragma unroll
    for (int n = 0; n < NEXP; ++n) logit[n] = acc[n] + br[n];
    bool used[NEXP];
#pragma unroll
    for (int n = 0; n < NEXP; ++n) used[n] = false;
    int se[NEXP]; float sw[NEXP];
    for (int j = 0; j < k; ++j) {           // strict > : lowest index wins ties (lax.top_k)
      int bi = 0; float bv = -INFINITY;
      for (int n = 0; n < NEXP; ++n)
        if (!used[n] && logit[n] > bv) { bv = logit[n]; bi = n; }
      used[bi] = true; se[j] = bi; sw[j] = bv;
    }
    float mx = sw[0], sum = 0.f;
    for (int j = 0; j < k; ++j) { sw[j] = expf(sw[j] - mx); sum += sw[j]; }
    float inv = 1.f / sum;
    for (int j = 0; j < k; ++j) {
      sel_e[t * 8 + j] = se[j];
      sel_w[t * 8 + j] = sw[j] * inv;
      wsel[wv][j] = se[j];
    }
  }
  __syncthreads();
  if (tid == 0) {
    int h[NEXP];
#pragma unroll
    for (int e = 0; e < NEXP; ++e) h[e] = 0;
    for (int w = 0; w < 4; ++w)
      for (int j = 0; j < k; ++j) {
        int e = wsel[w][j];
        sel_lpos[(blk * 4 + w) * 8 + j] = h[e]++;
      }
#pragma unroll
    for (int e = 0; e < NEXP; ++e) hist_blk[blk * NEXP + e] = h[e];
  }
}

// ---------- scan: per-expert exclusive scan over 1024 block hists ----------
__global__ void scan_k(const int* __restrict__ hist_blk, int* __restrict__ counts,
                       int* __restrict__ offsets, int* __restrict__ blk_base,
                       int* __restrict__ tmap) {
  __shared__ int sc[NEXP][257];
  __shared__ int offs[NEXP];
  const int tid = threadIdx.x;              // 256 threads, 4 hist rows each
  int h[4][NEXP], part[NEXP];
#pragma unroll
  for (int e = 0; e < NEXP; ++e) part[e] = 0;
#pragma unroll
  for (int r = 0; r < 4; ++r) {
    const int row = tid * 4 + r;
#pragma unroll
    for (int e = 0; e < NEXP; ++e) { h[r][e] = hist_blk[row * NEXP + e]; part[e] += h[r][e]; }
  }
#pragma unroll
  for (int e = 0; e < NEXP; ++e) sc[e][tid] = part[e];
  __syncthreads();
  for (int d = 1; d < 256; d <<= 1) {       // Hillis-Steele inclusive scan x8
    int v[NEXP];
#pragma unroll
    for (int e = 0; e < NEXP; ++e) v[e] = (tid >= d) ? sc[e][tid - d] : 0;
    __syncthreads();
#pragma unroll
    for (int e = 0; e < NEXP; ++e) sc[e][tid] += v[e];
    __syncthreads();
  }
  if (tid == 0) {
    int s = 0;
    for (int e = 0; e < NEXP; ++e) {
      int tot = sc[e][255];
      offsets[e] = s; offs[e] = s; counts[e] = tot; s += tot;
    }
    int nt = 0;
    for (int e = 0; e < NEXP; ++e) {
      int nb = (counts[e] + 255) >> 8;      // 256-row tiles
      for (int b = 0; b < nb && nt < MAXTILES; ++b) tmap[nt++] = (e << 16) | b;
    }
    for (; nt < MAXTILES; ++nt) tmap[nt] = -1;
  }
  __syncthreads();
#pragma unroll
  for (int e = 0; e < NEXP; ++e) {
    int run = offs[e] + sc[e][tid] - part[e];   // absolute exclusive base
#pragma unroll
    for (int r = 0; r < 4; ++r) {
      blk_base[(tid * 4 + r) * NEXP + e] = run;
      run += h[r][e];
    }
  }
}

// ---------- finalize: absolute positions + row->token scatter ----------
__global__ void finalize_k(const int* __restrict__ sel_e, const int* __restrict__ sel_lpos,
                           const int* __restrict__ blk_base, const int* __restrict__ topk_p,
                           int* __restrict__ sel_pos, int* __restrict__ row_token) {
  const int k = clampk(topk_p[0]);
  const int i = blockIdx.x * 256 + threadIdx.x;
  if (i >= TOKENS * k) return;
  const int t = i / k, j = i - t * k;
  const int e = sel_e[t * 8 + j];
  const int pos = blk_base[(t >> 2) * NEXP + e] + sel_lpos[t * 8 + j];
  sel_pos[t * 8 + j] = pos;                 // absolute compact-row index
  row_token[pos] = t;
}

// -------- gather+cast: xg[row] = bf16(x[row_token[row]]); zero pad rows; zero Y --------
__global__ void gather_cast_k(const float* __restrict__ x, const int* __restrict__ row_token,
                              const int* __restrict__ counts, u16* __restrict__ xg,
                              float* __restrict__ Y) {
  __shared__ int tot_s;
  if (threadIdx.x == 0) {
    int t = 0;
#pragma unroll
    for (int e = 0; e < NEXP; ++e) t += counts[e];
    tot_s = t;
  }
  const int row = blockIdx.x;
  const int i = threadIdx.x;                // 256 thr x 4 elems
  if (row < MAXROWS) {                      // fused Y zeroing (layer2 atomics need it)
    float4 z = {0.f, 0.f, 0.f, 0.f};
    *(float4*)(Y + (size_t)row * EDIM + i * 4) = z;
  }
  __syncthreads();
  u16* dst = xg + (size_t)row * EDIM;
  if (row >= tot_s) {                       // keep pads finite (tail tiles stage them)
    us4 z = {0, 0, 0, 0};
    *(us4*)(dst + i * 4) = z;
    return;
  }
  const float* src = x + (size_t)row_token[row] * EDIM;
  float4 v = *(const float4*)(src + i * 4);
  us4 o; o[0] = f2bf(v.x); o[1] = f2bf(v.y); o[2] = f2bf(v.z); o[3] = f2bf(v.w);
  *(us4*)(dst + i * 4) = o;
}

// ------ transpose+downcast 1024-wide H-chunks of W1 and W2 ------
__global__ void transpose_k(const float* __restrict__ W1, const float* __restrict__ W2,
                            u16* __restrict__ W1t, u16* __restrict__ W2t,
                            int full, int h0c) {
  __shared__ __align__(16) u16 T[64][68];   // +4 pad
  const int z = blockIdx.z;
  int mat, e, h0;
  if (full) { mat = z < 32 ? 0 : 1; int zz = mat ? z - 32 : z; e = zz >> 2; h0 = (zz & 3) * 1024; }
  else      { mat = z < 8 ? 0 : 1;  e = mat ? z - 8 : z;      h0 = h0c; }
  const size_t oes = full ? (size_t)HDIM * EDIM : (size_t)1024 * 1024;
  const float* in; size_t istride;
  if (mat == 0) { in = W1 + (size_t)e * EDIM * HDIM + h0;            istride = HDIM; }
  else          { in = W2 + (size_t)e * HDIM * EDIM + (size_t)h0 * EDIM; istride = EDIM; }
  const int r0 = blockIdx.y * 64, c0 = blockIdx.x * 64;
  const int tid = threadIdx.x;
#pragma unroll
  for (int it = 0; it < 4; ++it) {
    int cell = it * 256 + tid;              // 1024 cells: rl(64) x c4(16)
    int rl = cell >> 4, c4 = (cell & 15) * 4;
    float4 v = *(const float4*)(in + (size_t)(r0 + rl) * istride + c0 + c4);
    us4 o; o[0] = f2bf(v.x); o[1] = f2bf(v.y); o[2] = f2bf(v.z); o[3] = f2bf(v.w);
    *(us4*)&T[rl][c4] = o;
  }
  __syncthreads();
#pragma unroll
  for (int it = 0; it < 2; ++it) {
    int cell = it * 256 + tid;              // 512 cells: cl(64) x r8(8)
    int cl = cell >> 3, r8 = (cell & 7) * 8;
    us8 o;
#pragma unroll
    for (int j = 0; j < 8; ++j) o[j] = T[r8 + j][cl];
    u16* out;
    if (mat == 0) {  // W1t[e][h][ei]
      int orow = (full ? h0 : 0) + c0 + cl;
      out = W1t + (size_t)e * oes + (size_t)orow * 1024 + r0 + r8;
    } else {         // W2t[e][ep][h]
      int ost = full ? HDIM : 1024;
      out = W2t + (size_t)e * oes + (size_t)(c0 + cl) * ost + (full ? h0 : 0) + r0 + r8;
    }
    *(us8*)out = o;
  }
}

// -------- grouped 256x256 bf16 MFMA GEMM, BK=64, 2-phase double-buffered --------
// LDS 128KB: A[2 buf][256 rows][64 k] @0, B same @64KB. Swizzle: 16B-slot ^= row&7
// on the GLOBAL source of global_load_lds (LDS dest linear) and on ds_read offsets.
// Per K-tile: reads(A mi0-3 + B all) -> stage(t+1, buf^1) -> 32 MFMA ->
// reads(A mi4-7) -> 32 MFMA -> __syncthreads() (vmcnt(0)+lgkmcnt(0)+s_barrier;
// stage-to-drain distance ~2 MFMA clusters + reads -> HBM latency covered).
template <int MODE>
__global__ __launch_bounds__(512, 2) void gemm256_k(
    const u16* __restrict__ A, int astride, int kblocks,
    const u16* __restrict__ Bt, size_t b_estride, int bstride,
    const float* __restrict__ bias, int bias_dim, int bias_col0, int bias_on,
    const int* __restrict__ counts, const int* __restrict__ offsets,
    const int* __restrict__ tmap, int NB,
    u16* __restrict__ hid, int hid_stride, float* __restrict__ Y) {
  __shared__ __align__(16) char lds_s[131072];
  const int bid = blockIdx.x;               // n0-fastest; HW round-robin over XCDs
  const int by  = blockIdx.y;               // K-split index (layer2 full path)
  const int tile = bid / NB;
  const int tv = tmap[tile];
  if (tv < 0) return;
  const int n0 = (bid - tile * NB) << 8;
  const int e = tv >> 16;
  const int m0 = (tv & 0xffff) << 8;
  const int cnt = counts[e], off_e = offsets[e];

  const int tid = threadIdx.x;
  const int wv = tid >> 6, ln = tid & 63;
  const int wm = wv >> 2, wn = wv & 3;      // 2M x 4N wave grid; wave owns 128x64

  // ---- staging addressing: linear LDS dest, inverse-swizzled global source ----
  const int trow = tid >> 3;                // 0..63 rows per 8KB chunk
  const int swz  = (tid & 7) ^ (trow & 7);  // 16B slot permutation (involution)
  const size_t koff = (size_t)by * kblocks * 64;
  const u16* gA = A + (size_t)(off_e + m0 + trow) * astride + koff + swz * 8;
  const u16* gB = Bt + (size_t)e * b_estride + (size_t)(n0 + trow) * bstride + koff + swz * 8;
  const size_t a64 = (size_t)astride * 64;
  const size_t b64 = (size_t)bstride * 64;
  char* const lA = lds_s + wv * 1024;       // per-wave 1KB slice within each 8KB chunk
  char* const lB = lds_s + 65536 + wv * 1024;

  auto stage = [&](int buf, int kt) {       // full 256x64 A+B tile: 8 async16/wave
    const u16* ga = gA + (size_t)kt * 64;
    const u16* gb = gB + (size_t)kt * 64;
    char* la = lA + (buf << 15);
    char* lb = lB + (buf << 15);
#pragma unroll
    for (int h = 0; h < 4; ++h) async16(la + h * 8192, ga + (size_t)h * a64);
#pragma unroll
    for (int h = 0; h < 4; ++h) async16(lb + h * 8192, gb + (size_t)h * b64);
  };

  // ---- swizzled fragment read offsets (bytes) ----
  const int r15 = ln & 15, quad = ln >> 4, rs = r15 & 7;
  const int a_k0 = (wm * 128 + r15) * 128 + (((quad    ) ^ rs) << 4);
  const int a_k1 = (wm * 128 + r15) * 128 + (((quad + 4) ^ rs) << 4);
  const int b_k0 = (wn *  64 + r15) * 128 + (((quad    ) ^ rs) << 4);
  const int b_k1 = (wn *  64 + r15) * 128 + (((quad + 4) ^ rs) << 4);

  f32x4 acc[8][4];
#pragma unroll
  for (int i = 0; i < 8; ++i)
#pragma unroll
    for (int j = 0; j < 4; ++j) acc[i][j] = (f32x4){0.f, 0.f, 0.f, 0.f};

  bf16x8 a0[4], a1[4], b0[4], b1[4];

  stage(0, 0);
  __syncthreads();                          // drains vmcnt -> tile0 ready

  for (int t = 0; t < kblocks; ++t) {
    const int cb = (t & 1) << 15;
    const char* cA = lds_s + cb;
    const char* cB = lds_s + 65536 + cb;

    // reads: A rows mi0-3 (both k-halves) + all B
#pragma unroll
    for (int mi = 0; mi < 4; ++mi) {
      a0[mi] = *(const bf16x8*)(cA + a_k0 + mi * 2048);
      a1[mi] = *(const bf16x8*)(cA + a_k1 + mi * 2048);
    }
#pragma unroll
    for (int ni = 0; ni < 4; ++ni) {
      b0[ni] = *(const bf16x8*)(cB + b_k0 + ni * 2048);
      b1[ni] = *(const bf16x8*)(cB + b_k1 + ni * 2048);
    }
    if (t + 1 < kblocks) stage((t & 1) ^ 1, t + 1);  // issue-early, drained at sync

#pragma unroll
    for (int mi = 0; mi < 4; ++mi)
#pragma unroll
      for (int ni = 0; ni < 4; ++ni) {
        acc[mi][ni] = MFMA16(a0[mi], b0[ni], acc[mi][ni]);
        acc[mi][ni] = MFMA16(a1[mi], b1[ni], acc[mi][ni]);
      }

    // reads: A rows mi4-7 (reuse frag regs; keeps VGPR under 2-waves/SIMD budget)
#pragma unroll
    for (int mi = 0; mi < 4; ++mi) {
      a0[mi] = *(const bf16x8*)(cA + a_k0 + (mi + 4) * 2048);
      a1[mi] = *(const bf16x8*)(cA + a_k1 + (mi + 4) * 2048);
    }
#pragma unroll
    for (int mi = 0; mi < 4; ++mi)
#pragma unroll
      for (int ni = 0; ni < 4; ++ni) {
        acc[mi + 4][ni] = MFMA16(a0[mi], b0[ni], acc[mi + 4][ni]);
        acc[mi + 4][ni] = MFMA16(a1[mi], b1[ni], acc[mi + 4][ni]);
      }
    __syncthreads();                        // vmcnt(0)+lgkmcnt(0)+barrier: next buf ready
  }

  // ---- epilogue: D row = quad*4+r, col = r15 (m89/m91-verified layout) ----
  const int col0 = n0 + wn * 64 + r15;
  float bv[4];
#pragma unroll
  for (int ni = 0; ni < 4; ++ni) {
    const float b = bias[(size_t)e * bias_dim + bias_col0 + col0 + ni * 16];
    bv[ni] = (MODE == 0) ? b : ((bias_on && by == 0) ? b : 0.f);
  }
#pragma unroll
  for (int mi = 0; mi < 8; ++mi) {
    const int mb = m0 + wm * 128 + mi * 16 + quad * 4;
#pragma unroll
    for (int ni = 0; ni < 4; ++ni) {
      const int nc = col0 + ni * 16;
#pragma unroll
      for (int r = 0; r < 4; ++r) {
        const int m = mb + r;
        if (m < cnt) {
          const float v = acc[mi][ni][r] + bv[ni];
          if (MODE == 0) {
            hid[(size_t)(off_e + m) * hid_stride + nc] = f2bf(gelu_f(v));
          } else {
            atomicAdd(&Y[(size_t)(off_e + m) * EDIM + nc], v);
          }
        }
      }
    }
  }
}

// ---------------- weighted combine over top-k rows (absolute sel_pos) ----------------
__global__ void combine_k(const float* __restrict__ Y, const int* __restrict__ sel_pos,
                          const float* __restrict__ sel_w, const int* __restrict__ topk_p,
                          float* __restrict__ out) {
  const int t = blockIdx.x;
  const int tid = threadIdx.x;              // 256 thr x 4 floats
  const int k = clampk(topk_p[0]);
  float a0 = 0.f, a1 = 0.f, a2 = 0.f, a3 = 0.f;
  for (int j = 0; j < k; ++j) {
    const float w = sel_w[t * 8 + j];
    const size_t row = (size_t)sel_pos[t * 8 + j];
    const float4 v = *(const float4*)(Y + row * EDIM + tid * 4);
    a0 += w * v.x; a1 += w * v.y; a2 += w * v.z; a3 += w * v.w;
  }
  float4 o; o.x = a0; o.y = a1; o.z = a2; o.w = a3;
  *(float4*)(out + (size_t)t * EDIM + tid * 4) = o;
}

extern "C" void kernel_launch(void* const* d_in, const int* in_sizes, int n_in,
                              void* d_out, int out_size, void* d_ws, size_t ws_size,
                              hipStream_t stream) {
  const float* x   = (const float*)d_in[0];
  const float* Wr  = (const float*)d_in[1];
  const float* br  = (const float*)d_in[2];
  const float* W1  = (const float*)d_in[3];
  const float* b1  = (const float*)d_in[4];
  const float* W2  = (const float*)d_in[5];
  const float* b2  = (const float*)d_in[6];
  const int* topk  = (const int*)d_in[7];
  float* out = (float*)d_out;

  char* ws = (char*)d_ws;
  size_t o = 0;
  auto alloc = [&](size_t bytes) -> char* {
    char* p = ws + o; o += (bytes + 255) & ~(size_t)255; return p;
  };
  int*   counts    = (int*)alloc(NEXP * 4);
  int*   offsets   = (int*)alloc(NEXP * 4);
  int*   tmap      = (int*)alloc(MAXTILES * 4);
  int*   sel_e     = (int*)alloc((size_t)TOKENS * 8 * 4);
  int*   sel_pos   = (int*)alloc((size_t)TOKENS * 8 * 4);
  int*   sel_lpos  = (int*)alloc((size_t)TOKENS * 8 * 4);
  float* sel_w     = (float*)alloc((size_t)TOKENS * 8 * 4);
  int*   row_token = (int*)alloc((size_t)TOKENS * 8 * 4);
  int*   hist_blk  = (int*)alloc((size_t)RBLK * NEXP * 4);
  int*   blk_base  = (int*)alloc((size_t)RBLK * NEXP * 4);
  u16*   xg        = (u16*)alloc((size_t)(MAXROWS + ROWPAD) * EDIM * 2);  // 17.6 MB
  float* Y         = (float*)alloc((size_t)MAXROWS * EDIM * 4);           // 33.6 MB

  // decide path from remaining ws
  const size_t full_need  = ((size_t)NEXP * HDIM * EDIM * 2) * 2            // W1t+W2t 134.2 MB
                          + (size_t)(MAXROWS + ROWPAD) * HDIM * 2 + 4096;   // hid 70.3 MB
  const bool full = (ws_size - o) >= full_need;
  u16 *W1t, *W2t, *hid;
  if (full) {
    W1t = (u16*)alloc((size_t)NEXP * HDIM * EDIM * 2);
    W2t = (u16*)alloc((size_t)NEXP * HDIM * EDIM * 2);
    hid = (u16*)alloc((size_t)(MAXROWS + ROWPAD) * HDIM * 2);
  } else {
    W1t = (u16*)alloc((size_t)NEXP * 1024 * 1024 * 2);
    W2t = (u16*)alloc((size_t)NEXP * 1024 * 1024 * 2);
    hid = (u16*)alloc((size_t)(MAXROWS + ROWPAD) * 1024 * 2);
  }

  router_k<<<dim3(RBLK), dim3(256), 0, stream>>>(x, Wr, br, topk,
                                                 sel_e, sel_w, sel_lpos, hist_blk);
  scan_k<<<dim3(1), dim3(256), 0, stream>>>(hist_blk, counts, offsets, blk_base, tmap);
  finalize_k<<<dim3(TOKENS * 8 / 256), dim3(256), 0, stream>>>(sel_e, sel_lpos, blk_base,
                                                               topk, sel_pos, row_token);
  gather_cast_k<<<dim3(MAXROWS + ROWPAD), dim3(256), 0, stream>>>(x, row_token, counts,
                                                                  xg, Y);

  if (full) {
    transpose_k<<<dim3(16, 16, 64), dim3(256), 0, stream>>>(W1, W2, W1t, W2t, 1, 0);
    // layer 1: N=4096 merged, K=1024 (16 K-tiles)
    gemm256_k<0><<<dim3(MAXTILES * 16, 1), dim3(512), 0, stream>>>(
        xg, EDIM, 16, W1t, (size_t)HDIM * EDIM, EDIM,
        b1, HDIM, 0, 1, counts, offsets, tmap, 16, hid, HDIM, nullptr);
    // layer 2: K=4096 split 4 ways over blockIdx.y (16 K-tiles each), atomicAdd into Y
    gemm256_k<1><<<dim3(MAXTILES * 4, 4), dim3(512), 0, stream>>>(
        hid, HDIM, 16, W2t, (size_t)HDIM * EDIM, HDIM,
        b2, EDIM, 0, 1, counts, offsets, tmap, 4, nullptr, 0, Y);
  } else {
    for (int c = 0; c < 4; ++c) {
      const int h0 = c * 1024;
      transpose_k<<<dim3(16, 16, 16), dim3(256), 0, stream>>>(W1, W2, W1t, W2t, 0, h0);
      gemm256_k<0><<<dim3(MAXTILES * 4, 1), dim3(512), 0, stream>>>(
          xg, EDIM, 16, W1t, (size_t)1024 * 1024, 1024,
          b1, HDIM, h0, 1, counts, offsets, tmap, 4, hid, 1024, nullptr);
      gemm256_k<1><<<dim3(MAXTILES * 4, 1), dim3(512), 0, stream>>>(
          hid, 1024, 16, W2t, (size_t)1024 * 1024, 1024,
          b2, EDIM, 0, (c == 0) ? 1 : 0, counts, offsets, tmap, 4, nullptr, 0, Y);
    }
  }
  combine_k<<<dim3(TOKENS), dim3(256), 0, stream>>>(Y, sel_pos, sel_w, topk, out);
}

// Round 4
// 567.751 us; speedup vs baseline: 1.2111x; 1.1652x over previous
//
#include <hip/hip_runtime.h>
#include <hip/hip_bf16.h>
#include <cmath>
#include <cstdint>

// SparseMoE: B=2,S=2048 -> 4096 tokens, E=1024, N=8 experts, H=4096, top_k=2.
// R9 (resubmit; R3 bench was GPUAcquisitionTimeout — never ran): return to the
// measured-best structure (R6, m97-style 128x128 4-wave single-buffered grouped
// GEMM, 452 TF here) and remove its two measured taxes:
//   - BK=64 (was 32): halves barrier/drain count per block; 32KB LDS,
//     still 3 blocks/CU (launch_bounds(256,3); m114 inter-block overlap intact)
//   - T2 swizzle (16B-slot ^= row&7) on global_load_lds source + ds_read offsets:
//     R6 carried 8.78M bank-conflict cycles (8-way on b128); R7/R8 measured this
//     exact formula at 0 conflicts
//   - layer2: no KSPLIT, no atomics. 128-wide N-blocks -> 64 m-tiles x 8 = 512
//     real blocks (2/CU) single-pass K=4096 (64 K-iters amortization), plain store
//   - A&S erf gelu (exact to 1.5e-7), no Y pre-zero, no xcd swizzle

typedef unsigned short u16;
typedef __attribute__((ext_vector_type(8))) short bf16x8;   // MFMA A/B frag (4 VGPR)
typedef __attribute__((ext_vector_type(4))) float f32x4;    // MFMA C/D frag
typedef __attribute__((ext_vector_type(8))) unsigned short us8;
typedef __attribute__((ext_vector_type(4))) unsigned short us4;

#define TOKENS  4096
#define EDIM    1024
#define NEXP    8
#define HDIM    4096
#define MAXROWS 8192      // top_k(=2) * TOKENS
#define ROWPAD  128       // 128-row tile tail staging may read past cnt
#define MAXTILES 72       // sum ceil(cnt_e/128) <= 64 + 7
#define RBLK    1024      // router blocks (4 tokens each)

#define MFMA16(va, vb, vc) __builtin_amdgcn_mfma_f32_16x16x32_bf16(va, vb, vc, 0, 0, 0)

__device__ __forceinline__ u16 f2bf(float f) {
  __hip_bfloat16 h = __float2bfloat16(f);   // RNE
  return *reinterpret_cast<u16*>(&h);
}
__device__ __forceinline__ int clampk(int k) {
  return k < 1 ? 1 : (k > 8 ? 8 : k);
}
// async global->LDS, 16B/lane; LDS dest = wave-uniform base + lane*16 (HW rule)
__device__ __forceinline__ void async16(void* lds, const void* g) {
  __builtin_amdgcn_global_load_lds((const __attribute__((address_space(1))) void*)g,
                                   (__attribute__((address_space(3))) void*)lds,
                                   16, 0, 0);
}
// exact gelu via A&S 7.1.26 erf (|eps|<=1.5e-7), ~12 VALU ops
__device__ __forceinline__ float gelu_f(float v) {
  const float z = fabsf(v) * 0.70710678118654752f;
  const float t = __builtin_amdgcn_rcpf(fmaf(0.3275911f, z, 1.0f));
  const float p = t * fmaf(t, fmaf(t, fmaf(t, fmaf(t, 1.061405429f, -1.453152027f),
                                           1.421413741f), -0.284496736f), 0.254829592f);
  float er = 1.0f - p * __expf(-z * z);
  er = copysignf(er, v);
  return 0.5f * v * (1.0f + er);
}

// ---------- router: logits + top-k + softmax + block-local hist (no atomics) ----------
__global__ void router_k(const float* __restrict__ x, const float* __restrict__ Wr,
                         const float* __restrict__ br, const int* __restrict__ topk_p,
                         int* __restrict__ sel_e, float* __restrict__ sel_w,
                         int* __restrict__ sel_lpos, int* __restrict__ hist_blk) {
  __shared__ int wsel[4][8];
  const int blk = blockIdx.x;
  const int tid = threadIdx.x;
  const int wv = tid >> 6, ln = tid & 63;
  const int t = blk * 4 + wv;
  const int k = clampk(topk_p[0]);
  float acc[NEXP];
#pragma unroll
  for (int n = 0; n < NEXP; ++n) acc[n] = 0.f;
  const float* xr = x + (size_t)t * EDIM;
  for (int ei = ln; ei < EDIM; ei += 64) {
    float xv = xr[ei];
    float4 w0 = *(const float4*)(Wr + ei * NEXP);
    float4 w1 = *(const float4*)(Wr + ei * NEXP + 4);
    acc[0] += xv * w0.x; acc[1] += xv * w0.y; acc[2] += xv * w0.z; acc[3] += xv * w0.w;
    acc[4] += xv * w1.x; acc[5] += xv * w1.y; acc[6] += xv * w1.z; acc[7] += xv * w1.w;
  }
#pragma unroll
  for (int s = 32; s > 0; s >>= 1) {
#pragma unroll
    for (int n = 0; n < NEXP; ++n) acc[n] += __shfl_down(acc[n], s);
  }
  if (ln == 0) {
    float logit[NEXP];
#pragma unroll
    for (int n = 0; n < NEXP; ++n) logit[n] = acc[n] + br[n];
    bool used[NEXP];
#pragma unroll
    for (int n = 0; n < NEXP; ++n) used[n] = false;
    int se[NEXP]; float sw[NEXP];
    for (int j = 0; j < k; ++j) {           // strict > : lowest index wins ties (lax.top_k)
      int bi = 0; float bv = -INFINITY;
      for (int n = 0; n < NEXP; ++n)
        if (!used[n] && logit[n] > bv) { bv = logit[n]; bi = n; }
      used[bi] = true; se[j] = bi; sw[j] = bv;
    }
    float mx = sw[0], sum = 0.f;
    for (int j = 0; j < k; ++j) { sw[j] = expf(sw[j] - mx); sum += sw[j]; }
    float inv = 1.f / sum;
    for (int j = 0; j < k; ++j) {
      sel_e[t * 8 + j] = se[j];
      sel_w[t * 8 + j] = sw[j] * inv;
      wsel[wv][j] = se[j];
    }
  }
  __syncthreads();
  if (tid == 0) {
    int h[NEXP];
#pragma unroll
    for (int e = 0; e < NEXP; ++e) h[e] = 0;
    for (int w = 0; w < 4; ++w)
      for (int j = 0; j < k; ++j) {
        int e = wsel[w][j];
        sel_lpos[(blk * 4 + w) * 8 + j] = h[e]++;
      }
#pragma unroll
    for (int e = 0; e < NEXP; ++e) hist_blk[blk * NEXP + e] = h[e];
  }
}

// ---------- scan: per-expert exclusive scan over 1024 block hists ----------
__global__ void scan_k(const int* __restrict__ hist_blk, int* __restrict__ counts,
                       int* __restrict__ offsets, int* __restrict__ blk_base,
                       int* __restrict__ tmap) {
  __shared__ int sc[NEXP][257];
  __shared__ int offs[NEXP];
  const int tid = threadIdx.x;              // 256 threads, 4 hist rows each
  int h[4][NEXP], part[NEXP];
#pragma unroll
  for (int e = 0; e < NEXP; ++e) part[e] = 0;
#pragma unroll
  for (int r = 0; r < 4; ++r) {
    const int row = tid * 4 + r;
#pragma unroll
    for (int e = 0; e < NEXP; ++e) { h[r][e] = hist_blk[row * NEXP + e]; part[e] += h[r][e]; }
  }
#pragma unroll
  for (int e = 0; e < NEXP; ++e) sc[e][tid] = part[e];
  __syncthreads();
  for (int d = 1; d < 256; d <<= 1) {       // Hillis-Steele inclusive scan x8
    int v[NEXP];
#pragma unroll
    for (int e = 0; e < NEXP; ++e) v[e] = (tid >= d) ? sc[e][tid - d] : 0;
    __syncthreads();
#pragma unroll
    for (int e = 0; e < NEXP; ++e) sc[e][tid] += v[e];
    __syncthreads();
  }
  if (tid == 0) {
    int s = 0;
    for (int e = 0; e < NEXP; ++e) {
      int tot = sc[e][255];
      offsets[e] = s; offs[e] = s; counts[e] = tot; s += tot;
    }
    int nt = 0;
    for (int e = 0; e < NEXP; ++e) {
      int nb = (counts[e] + 127) >> 7;      // 128-row tiles
      for (int b = 0; b < nb && nt < MAXTILES; ++b) tmap[nt++] = (e << 16) | b;
    }
    for (; nt < MAXTILES; ++nt) tmap[nt] = -1;
  }
  __syncthreads();
#pragma unroll
  for (int e = 0; e < NEXP; ++e) {
    int run = offs[e] + sc[e][tid] - part[e];   // absolute exclusive base
#pragma unroll
    for (int r = 0; r < 4; ++r) {
      blk_base[(tid * 4 + r) * NEXP + e] = run;
      run += h[r][e];
    }
  }
}

// ---------- finalize: absolute positions + row->token scatter ----------
__global__ void finalize_k(const int* __restrict__ sel_e, const int* __restrict__ sel_lpos,
                           const int* __restrict__ blk_base, const int* __restrict__ topk_p,
                           int* __restrict__ sel_pos, int* __restrict__ row_token) {
  const int k = clampk(topk_p[0]);
  const int i = blockIdx.x * 256 + threadIdx.x;
  if (i >= TOKENS * k) return;
  const int t = i / k, j = i - t * k;
  const int e = sel_e[t * 8 + j];
  const int pos = blk_base[(t >> 2) * NEXP + e] + sel_lpos[t * 8 + j];
  sel_pos[t * 8 + j] = pos;                 // absolute compact-row index
  row_token[pos] = t;
}

// ---------------- gather+cast: xg[row] = bf16(x[row_token[row]]); zero pad rows ----------------
__global__ void gather_cast_k(const float* __restrict__ x, const int* __restrict__ row_token,
                              const int* __restrict__ counts, u16* __restrict__ xg) {
  __shared__ int tot_s;
  if (threadIdx.x == 0) {
    int t = 0;
#pragma unroll
    for (int e = 0; e < NEXP; ++e) t += counts[e];
    tot_s = t;
  }
  __syncthreads();
  const int row = blockIdx.x;
  u16* dst = xg + (size_t)row * EDIM;
  const int i = threadIdx.x;                // 256 thr x 4 elems
  if (row >= tot_s) {                       // keep pads finite (tail tiles stage them)
    us4 z = {0, 0, 0, 0};
    *(us4*)(dst + i * 4) = z;
    return;
  }
  const float* src = x + (size_t)row_token[row] * EDIM;
  float4 v = *(const float4*)(src + i * 4);
  us4 o; o[0] = f2bf(v.x); o[1] = f2bf(v.y); o[2] = f2bf(v.z); o[3] = f2bf(v.w);
  *(us4*)(dst + i * 4) = o;
}

// ------ transpose+downcast 1024-wide H-chunks of W1 and W2 ------
__global__ void transpose_k(const float* __restrict__ W1, const float* __restrict__ W2,
                            u16* __restrict__ W1t, u16* __restrict__ W2t,
                            int full, int h0c) {
  __shared__ __align__(16) u16 T[64][68];   // +4 pad
  const int z = blockIdx.z;
  int mat, e, h0;
  if (full) { mat = z < 32 ? 0 : 1; int zz = mat ? z - 32 : z; e = zz >> 2; h0 = (zz & 3) * 1024; }
  else      { mat = z < 8 ? 0 : 1;  e = mat ? z - 8 : z;      h0 = h0c; }
  const size_t oes = full ? (size_t)HDIM * EDIM : (size_t)1024 * 1024;
  const float* in; size_t istride;
  if (mat == 0) { in = W1 + (size_t)e * EDIM * HDIM + h0;            istride = HDIM; }
  else          { in = W2 + (size_t)e * HDIM * EDIM + (size_t)h0 * EDIM; istride = EDIM; }
  const int r0 = blockIdx.y * 64, c0 = blockIdx.x * 64;
  const int tid = threadIdx.x;
#pragma unroll
  for (int it = 0; it < 4; ++it) {
    int cell = it * 256 + tid;              // 1024 cells: rl(64) x c4(16)
    int rl = cell >> 4, c4 = (cell & 15) * 4;
    float4 v = *(const float4*)(in + (size_t)(r0 + rl) * istride + c0 + c4);
    us4 o; o[0] = f2bf(v.x); o[1] = f2bf(v.y); o[2] = f2bf(v.z); o[3] = f2bf(v.w);
    *(us4*)&T[rl][c4] = o;
  }
  __syncthreads();
#pragma unroll
  for (int it = 0; it < 2; ++it) {
    int cell = it * 256 + tid;              // 512 cells: cl(64) x r8(8)
    int cl = cell >> 3, r8 = (cell & 7) * 8;
    us8 o;
#pragma unroll
    for (int j = 0; j < 8; ++j) o[j] = T[r8 + j][cl];
    u16* out;
    if (mat == 0) {  // W1t[e][h][ei]
      int orow = (full ? h0 : 0) + c0 + cl;
      out = W1t + (size_t)e * oes + (size_t)orow * 1024 + r0 + r8;
    } else {         // W2t[e][ep][h]
      int ost = full ? HDIM : 1024;
      out = W2t + (size_t)e * oes + (size_t)(c0 + cl) * ost + (full ? h0 : 0) + r0 + r8;
    }
    *(us8*)out = o;
  }
}

// -------- grouped 128x128 bf16 MFMA GEMM, BK=64, 4-wave, single-buffered --------
// LDS 32KB: As/Bs [128 rows][64 k] linear (128B rows). Swizzle: 16B-slot ^= row&7
// on the GLOBAL source of global_load_lds (LDS dest linear) and on ds_read offsets
// (R7/R8-measured: 0 bank conflicts on this exact read pattern).
// Per K-tile: sync; stage 8x async16/thread (A+B, 32KB); sync (vmcnt drain);
// 16x ds_read_b128; 32 MFMA. 3 blocks/CU resident (launch_bounds 256,3) provide
// the m114 inter-block overlap that hides the per-tile drain.
template <int MODE>
__global__ __launch_bounds__(256, 3) void gemm_k(
    const u16* __restrict__ A, int astride, int kblocks,
    const u16* __restrict__ Bt, size_t b_estride, int bstride,
    const float* __restrict__ bias, int bias_dim, int bias_col0, int bias_on,
    const int* __restrict__ counts, const int* __restrict__ offsets,
    const int* __restrict__ tmap, int NB,
    u16* __restrict__ hid, int hid_stride, float* __restrict__ Y, int accum) {
  __shared__ __align__(16) u16 As[128 * 64];   // 16 KB
  __shared__ __align__(16) u16 Bs[128 * 64];   // 16 KB
  const int bid = blockIdx.x;               // n0-fastest; HW round-robin over XCDs
  const int tile = bid / NB;
  const int tv = tmap[tile];
  if (tv < 0) return;
  const int n0 = (bid - tile * NB) << 7;
  const int e = tv >> 16;
  const int m0 = (tv & 0xffff) << 7;
  const int cnt = counts[e], off_e = offsets[e];

  const int tid = threadIdx.x;
  const int wv = tid >> 6, ln = tid & 63;
  const int wm = wv >> 1, wn = wv & 1;      // 2M x 2N wave grid; wave owns 64x64

  // ---- staging: linear LDS dest, inverse-swizzled global source ----
  const int trow = tid >> 3;                // 0..31 rows per async16 pass
  const int swz  = (tid & 7) ^ (trow & 7);  // 16B slot permutation (involution)
  const u16* gA = A + (size_t)(off_e + m0 + trow) * astride + swz * 8;
  const u16* gB = Bt + (size_t)e * b_estride + (size_t)(n0 + trow) * bstride + swz * 8;
  const size_t a32 = (size_t)astride * 32;
  const size_t b32 = (size_t)bstride * 32;
  u16* const lA = As + wv * 512;            // wave-uniform; +h*2048 per pass
  u16* const lB = Bs + wv * 512;

  // ---- swizzled fragment read offsets (u16 units; row stride 64) ----
  const int r15 = ln & 15, quad = ln >> 4, rs = r15 & 7;
  const int arow = (wm * 64 + r15) * 64;    // + mi*1024
  const int brow = (wn * 64 + r15) * 64;    // + ni*1024
  const int s0 = (quad ^ rs) * 8;           // k-half 0 slot
  const int s1 = ((quad + 4) ^ rs) * 8;     // k-half 1 slot

  f32x4 acc[4][4];
#pragma unroll
  for (int i = 0; i < 4; ++i)
#pragma unroll
    for (int j = 0; j < 4; ++j) acc[i][j] = (f32x4){0.f, 0.f, 0.f, 0.f};

  for (int kb = 0; kb < kblocks; ++kb) {
    const int k0 = kb * 64;
    __syncthreads();                        // prev iter's LDS reads done
    const u16* ga = gA + k0;
    const u16* gb = gB + k0;
#pragma unroll
    for (int h = 0; h < 4; ++h) async16(lA + h * 2048, ga + (size_t)h * a32);
#pragma unroll
    for (int h = 0; h < 4; ++h) async16(lB + h * 2048, gb + (size_t)h * b32);
    __syncthreads();                        // drains vmcnt -> LDS ready

    bf16x8 a0[4], a1[4], b0[4], b1[4];
#pragma unroll
    for (int mi = 0; mi < 4; ++mi) {
      a0[mi] = *(const bf16x8*)(As + arow + mi * 1024 + s0);
      a1[mi] = *(const bf16x8*)(As + arow + mi * 1024 + s1);
    }
#pragma unroll
    for (int ni = 0; ni < 4; ++ni) {
      b0[ni] = *(const bf16x8*)(Bs + brow + ni * 1024 + s0);
      b1[ni] = *(const bf16x8*)(Bs + brow + ni * 1024 + s1);
    }
#pragma unroll
    for (int mi = 0; mi < 4; ++mi)
#pragma unroll
      for (int ni = 0; ni < 4; ++ni) {
        acc[mi][ni] = MFMA16(a0[mi], b0[ni], acc[mi][ni]);
        acc[mi][ni] = MFMA16(a1[mi], b1[ni], acc[mi][ni]);
      }
  }

  // ---- epilogue: D row = quad*4+r, col = r15 (m89/m91-verified layout) ----
  const int col0 = n0 + wn * 64 + r15;
  float bv[4];
#pragma unroll
  for (int ni = 0; ni < 4; ++ni) {
    const float b = bias[(size_t)e * bias_dim + bias_col0 + col0 + ni * 16];
    bv[ni] = (MODE == 0) ? b : (bias_on ? b : 0.f);
  }
#pragma unroll
  for (int mi = 0; mi < 4; ++mi) {
    const int mb = m0 + wm * 64 + mi * 16 + quad * 4;
#pragma unroll
    for (int ni = 0; ni < 4; ++ni) {
      const int nc = col0 + ni * 16;
#pragma unroll
      for (int r = 0; r < 4; ++r) {
        const int m = mb + r;
        if (m < cnt) {
          const float v = acc[mi][ni][r] + bv[ni];
          if (MODE == 0) {
            hid[(size_t)(off_e + m) * hid_stride + nc] = f2bf(gelu_f(v));
          } else {
            size_t yi = (size_t)(off_e + m) * EDIM + nc;
            Y[yi] = accum ? (Y[yi] + v) : v;
          }
        }
      }
    }
  }
}

// ---------------- weighted combine over top-k rows (absolute sel_pos) ----------------
__global__ void combine_k(const float* __restrict__ Y, const int* __restrict__ sel_pos,
                          const float* __restrict__ sel_w, const int* __restrict__ topk_p,
                          float* __restrict__ out) {
  const int t = blockIdx.x;
  const int tid = threadIdx.x;              // 256 thr x 4 floats
  const int k = clampk(topk_p[0]);
  float a0 = 0.f, a1 = 0.f, a2 = 0.f, a3 = 0.f;
  for (int j = 0; j < k; ++j) {
    const float w = sel_w[t * 8 + j];
    const size_t row = (size_t)sel_pos[t * 8 + j];
    const float4 v = *(const float4*)(Y + row * EDIM + tid * 4);
    a0 += w * v.x; a1 += w * v.y; a2 += w * v.z; a3 += w * v.w;
  }
  float4 o; o.x = a0; o.y = a1; o.z = a2; o.w = a3;
  *(float4*)(out + (size_t)t * EDIM + tid * 4) = o;
}

extern "C" void kernel_launch(void* const* d_in, const int* in_sizes, int n_in,
                              void* d_out, int out_size, void* d_ws, size_t ws_size,
                              hipStream_t stream) {
  const float* x   = (const float*)d_in[0];
  const float* Wr  = (const float*)d_in[1];
  const float* br  = (const float*)d_in[2];
  const float* W1  = (const float*)d_in[3];
  const float* b1  = (const float*)d_in[4];
  const float* W2  = (const float*)d_in[5];
  const float* b2  = (const float*)d_in[6];
  const int* topk  = (const int*)d_in[7];
  float* out = (float*)d_out;

  char* ws = (char*)d_ws;
  size_t o = 0;
  auto alloc = [&](size_t bytes) -> char* {
    char* p = ws + o; o += (bytes + 255) & ~(size_t)255; return p;
  };
  int*   counts    = (int*)alloc(NEXP * 4);
  int*   offsets   = (int*)alloc(NEXP * 4);
  int*   tmap      = (int*)alloc(MAXTILES * 4);
  int*   sel_e     = (int*)alloc((size_t)TOKENS * 8 * 4);
  int*   sel_pos   = (int*)alloc((size_t)TOKENS * 8 * 4);
  int*   sel_lpos  = (int*)alloc((size_t)TOKENS * 8 * 4);
  float* sel_w     = (float*)alloc((size_t)TOKENS * 8 * 4);
  int*   row_token = (int*)alloc((size_t)TOKENS * 8 * 4);
  int*   hist_blk  = (int*)alloc((size_t)RBLK * NEXP * 4);
  int*   blk_base  = (int*)alloc((size_t)RBLK * NEXP * 4);
  u16*   xg        = (u16*)alloc((size_t)(MAXROWS + ROWPAD) * EDIM * 2);  // 17.0 MB
  float* Y         = (float*)alloc((size_t)MAXROWS * EDIM * 4);           // 33.6 MB

  // decide path from remaining ws
  const size_t full_need  = ((size_t)NEXP * HDIM * EDIM * 2) * 2            // W1t+W2t 134.2 MB
                          + (size_t)(MAXROWS + ROWPAD) * HDIM * 2 + 4096;   // hid 68.2 MB
  const bool full = (ws_size - o) >= full_need;
  u16 *W1t, *W2t, *hid;
  if (full) {
    W1t = (u16*)alloc((size_t)NEXP * HDIM * EDIM * 2);
    W2t = (u16*)alloc((size_t)NEXP * HDIM * EDIM * 2);
    hid = (u16*)alloc((size_t)(MAXROWS + ROWPAD) * HDIM * 2);
  } else {
    W1t = (u16*)alloc((size_t)NEXP * 1024 * 1024 * 2);
    W2t = (u16*)alloc((size_t)NEXP * 1024 * 1024 * 2);
    hid = (u16*)alloc((size_t)(MAXROWS + ROWPAD) * 1024 * 2);
  }

  router_k<<<dim3(RBLK), dim3(256), 0, stream>>>(x, Wr, br, topk,
                                                 sel_e, sel_w, sel_lpos, hist_blk);
  scan_k<<<dim3(1), dim3(256), 0, stream>>>(hist_blk, counts, offsets, blk_base, tmap);
  finalize_k<<<dim3(TOKENS * 8 / 256), dim3(256), 0, stream>>>(sel_e, sel_lpos, blk_base,
                                                               topk, sel_pos, row_token);
  gather_cast_k<<<dim3(MAXROWS + ROWPAD), dim3(256), 0, stream>>>(x, row_token, counts, xg);

  if (full) {
    transpose_k<<<dim3(16, 16, 64), dim3(256), 0, stream>>>(W1, W2, W1t, W2t, 1, 0);
    // layer 1: N=4096 merged (NB=32), K=1024 (16 K-tiles)
    gemm_k<0><<<dim3(MAXTILES * 32), dim3(256), 0, stream>>>(
        xg, EDIM, 16, W1t, (size_t)HDIM * EDIM, 1024,
        b1, HDIM, 0, 1, counts, offsets, tmap, 32, hid, HDIM, nullptr, 0);
    // layer 2: K=4096 single pass (64 K-tiles), NB=8, plain store
    gemm_k<1><<<dim3(MAXTILES * 8), dim3(256), 0, stream>>>(
        hid, HDIM, 64, W2t, (size_t)HDIM * EDIM, HDIM,
        b2, EDIM, 0, 1, counts, offsets, tmap, 8, nullptr, 0, Y, 0);
  } else {
    for (int c = 0; c < 4; ++c) {
      const int h0 = c * 1024;
      transpose_k<<<dim3(16, 16, 16), dim3(256), 0, stream>>>(W1, W2, W1t, W2t, 0, h0);
      gemm_k<0><<<dim3(MAXTILES * 8), dim3(256), 0, stream>>>(
          xg, EDIM, 16, W1t, (size_t)1024 * 1024, 1024,
          b1, HDIM, h0, 1, counts, offsets, tmap, 8, hid, 1024, nullptr, 0);
      gemm_k<1><<<dim3(MAXTILES * 8), dim3(256), 0, stream>>>(
          hid, 1024, 16, W2t, (size_t)1024 * 1024, 1024,
          b2, EDIM, 0, (c == 0) ? 1 : 0, counts, offsets, tmap, 8, nullptr, 0, Y,
          (c == 0) ? 0 : 1);
    }
  }
  combine_k<<<dim3(TOKENS), dim3(256), 0, stream>>>(Y, sel_pos, sel_w, topk, out);
}